// Round 6
// baseline (125.263 us; speedup 1.0000x reference)
//
#include <hip/hip_runtime.h>
#include <math.h>

#define HH 512
#define WW 512
#define PP (HH * WW)          // 262144 pixels
#define GG 64                 // gt points per batch
#define BB 4                  // batches
#define THREADS 256
#define TILE 1024             // pixels per block
#define NT (PP / TILE)        // 256 tiles per batch
#define MAX_DIST 724.0773439350246f   // sqrt(512^2 + 512^2)
#define EPSV 1e-6f

// ws float layout (partials, no init needed — write-only from main):
//   t1p  [BB][NT]      : ws[0    .. 1023]
//   nep  [BB][NT]      : ws[1024 .. 2047]
//   gminp[BB][NT][GG]  : ws[2048 .. 2048 + 65535]

__launch_bounds__(THREADS)
__global__ void ghd_main(const float* __restrict__ prob_map,
                         const float* __restrict__ prob_y,
                         const float* __restrict__ gt,
                         const int*   __restrict__ osz,
                         float*       __restrict__ ws) {
    const int t    = blockIdx.x;   // tile
    const int b    = blockIdx.y;   // batch
    const int tid  = threadIdx.x;
    const int lane = tid & 63;
    const int wave = tid >> 6;

    __shared__ float4 gdat[GG];        // (ny0, ny1, py, py^2)
    __shared__ float4 sdat[TILE];      // (nx0, nx1, p, base) per pixel
    __shared__ float  wmin[4][GG];
    __shared__ float  s_t1[4], s_ne[4];

    const float nf0 = (float)osz[2 * b]     * (1.0f / HH);
    const float nf1 = (float)osz[2 * b + 1] * (1.0f / WW);

    if (tid < GG) {
        float py = prob_y[b * GG + tid];
        gdat[tid] = make_float4(nf0 * gt[(b * GG + tid) * 2],
                                nf1 * gt[(b * GG + tid) * 2 + 1],
                                py, py * py);
    }

    // ---- stage this block's tile; keep own 4 pixels in registers ----
    const int   pid0 = t * TILE + tid * 4;
    const float4 p4  = ((const float4*)(prob_map + (size_t)b * PP))[pid0 >> 2];
    const float nx0  = nf0 * (float)(pid0 >> 9);
    const float j0   = (float)(pid0 & (WW - 1));
    const float nx1a = nf1 * j0;
    const float nx1b = nf1 * (j0 + 1.0f);
    const float nx1c = nf1 * (j0 + 2.0f);
    const float nx1d = nf1 * (j0 + 3.0f);
    const float bsa = fmaf(-p4.x, MAX_DIST, MAX_DIST);
    const float bsb = fmaf(-p4.y, MAX_DIST, MAX_DIST);
    const float bsc = fmaf(-p4.z, MAX_DIST, MAX_DIST);
    const float bsd = fmaf(-p4.w, MAX_DIST, MAX_DIST);
    sdat[tid * 4 + 0] = make_float4(nx0, nx1a, p4.x, bsa);
    sdat[tid * 4 + 1] = make_float4(nx0, nx1b, p4.y, bsb);
    sdat[tid * 4 + 2] = make_float4(nx0, nx1c, p4.z, bsc);
    sdat[tid * 4 + 3] = make_float4(nx0, nx1d, p4.w, bsd);
    __syncthreads();

    // ================= A: term-1 on own 4 pixels (registers + gdat) ==========
    float ma = 3.4e38f, mb = 3.4e38f, mc = 3.4e38f, md = 3.4e38f;
#pragma unroll 16
    for (int g = 0; g < GG; ++g) {
        float4 gd  = gdat[g];
        float  dx  = nx0 - gd.x;
        float  dx2 = dx * dx;
        float  da = nx1a - gd.y, db = nx1b - gd.y;
        float  dc = nx1c - gd.y, dd = nx1d - gd.y;
        ma = fminf(ma, gd.w * fmaf(da, da, dx2));   // min_g (py^2 * d^2)
        mb = fminf(mb, gd.w * fmaf(db, db, dx2));
        mc = fminf(mc, gd.w * fmaf(dc, dc, dx2));
        md = fminf(md, gd.w * fmaf(dd, dd, dx2));
    }
    float t1 = p4.x * __builtin_amdgcn_sqrtf(ma) + p4.y * __builtin_amdgcn_sqrtf(mb)
             + p4.z * __builtin_amdgcn_sqrtf(mc) + p4.w * __builtin_amdgcn_sqrtf(md);
    float ne = p4.x + p4.y + p4.z + p4.w;

    // ================= B: term-2, lane owns g, wave scans tile quarter =======
    const float4 gme = gdat[lane];      // gx, gy, py
    float gmin = 3.4e38f;
    const float4* __restrict__ tp = &sdat[wave * (TILE / 4)];
#pragma unroll 4
    for (int k = 0; k < TILE / 4; k += 4) {
        float4 x0 = tp[k], x1 = tp[k + 1], x2 = tp[k + 2], x3 = tp[k + 3];
        float mbse = fminf(fminf(x0.w, x1.w), fminf(x2.w, x3.w));
        if (!__all(mbse >= gmin)) {
            float d0x = x0.x - gme.x, d0y = x0.y - gme.y;
            float d1x = x1.x - gme.x, d1y = x1.y - gme.y;
            float d2x = x2.x - gme.x, d2y = x2.y - gme.y;
            float d3x = x3.x - gme.x, d3y = x3.y - gme.y;
            float e0 = __builtin_amdgcn_sqrtf(fmaf(d0x, d0x, d0y * d0y));
            float e1 = __builtin_amdgcn_sqrtf(fmaf(d1x, d1x, d1y * d1y));
            float e2 = __builtin_amdgcn_sqrtf(fmaf(d2x, d2x, d2y * d2y));
            float e3 = __builtin_amdgcn_sqrtf(fmaf(d3x, d3x, d3y * d3y));
            gmin = fminf(gmin, fmaf(x0.z * gme.z, e0, x0.w));
            gmin = fminf(gmin, fmaf(x1.z * gme.z, e1, x1.w));
            gmin = fminf(gmin, fmaf(x2.z * gme.z, e2, x2.w));
            gmin = fminf(gmin, fmaf(x3.z * gme.z, e3, x3.w));
        }
    }
    wmin[wave][lane] = gmin;

    // ================= block reductions -> per-(b,tile) partials =============
#pragma unroll
    for (int off = 1; off < 64; off <<= 1) {
        t1 += __shfl_xor(t1, off);
        ne += __shfl_xor(ne, off);
    }
    if (lane == 0) { s_t1[wave] = t1; s_ne[wave] = ne; }
    __syncthreads();

    if (tid == 0) {
        ws[b * NT + t]        = s_t1[0] + s_t1[1] + s_t1[2] + s_t1[3];
        ws[1024 + b * NT + t] = s_ne[0] + s_ne[1] + s_ne[2] + s_ne[3];
    }
    if (tid < GG) {
        float v = fminf(fminf(wmin[0][tid], wmin[1][tid]),
                        fminf(wmin[2][tid], wmin[3][tid]));
        ws[2048 + (b * NT + t) * GG + tid] = v;
    }
}

__global__ void ghd_final(const float* __restrict__ prob_y,
                          const float* __restrict__ ws,
                          float*       __restrict__ out) {
    // 256 threads: wave b handles batch b, lane = g
    const int tid = threadIdx.x;
    const int b = tid >> 6;
    const int g = tid & 63;

    // per-g min over 256 tile partials
    float mv = 3.4e38f;
    const float* gp = ws + 2048 + b * NT * GG + g;
#pragma unroll 8
    for (int t = 0; t < NT; ++t) mv = fminf(mv, gp[t * GG]);

    float py  = prob_y[b * GG + g];
    float pyf = (py > 0.2f) ? py : 0.0f;

    // t1 / ne partial sums: lane loads float4 (64 lanes x 4 = 256 tiles)
    float4 tv = ((const float4*)(ws + b * NT))[g];
    float4 nv = ((const float4*)(ws + 1024 + b * NT))[g];
    float t1s = tv.x + tv.y + tv.z + tv.w;
    float nes = nv.x + nv.y + nv.z + nv.w;

#pragma unroll
    for (int off = 1; off < 64; off <<= 1) {
        mv  += __shfl_xor(mv, off);
        pyf += __shfl_xor(pyf, off);
        t1s += __shfl_xor(t1s, off);
        nes += __shfl_xor(nes, off);
    }
    __shared__ float res[4];
    if (g == 0) res[b] = t1s / (nes + EPSV) + mv / (pyf + EPSV);
    __syncthreads();
    if (tid == 0) out[0] = 0.25f * (res[0] + res[1] + res[2] + res[3]);
}

extern "C" void kernel_launch(void* const* d_in, const int* in_sizes, int n_in,
                              void* d_out, int out_size, void* d_ws, size_t ws_size,
                              hipStream_t stream) {
    const float* prob_map = (const float*)d_in[0];
    const float* prob_y   = (const float*)d_in[1];
    const float* gt       = (const float*)d_in[2];
    const int*   osz      = (const int*)d_in[3];
    float* out = (float*)d_out;
    float* ws  = (float*)d_ws;

    dim3 grid(NT, BB);
    ghd_main<<<grid, THREADS, 0, stream>>>(prob_map, prob_y, gt, osz, ws);
    ghd_final<<<1, 256, 0, stream>>>(prob_y, ws, out);
}

// Round 9
// 93.383 us; speedup vs baseline: 1.3414x; 1.3414x over previous
//
#include <hip/hip_runtime.h>
#include <math.h>

#define HH 512
#define WW 512
#define PP (HH * WW)          // 262144 pixels
#define GG 64                 // gt points per batch
#define BB 4                  // batches
#define THREADS 256
#define TILE 1024             // pixels per block
#define NT (PP / TILE)        // 256 tiles per batch
#define MAX_DIST 724.0773439350246f   // sqrt(512^2 + 512^2)
#define EPSV 1e-6f

// ws layout:
//   gm  uint bits [BB][GG] : ws[0    .. 255]    (init 0x7f7f7f7f via memset — > any dense value)
//   t1p [BB][NT]           : ws[256  .. 1279]   (write-only partials, no init)
//   nep [BB][NT]           : ws[1280 .. 2303]

__launch_bounds__(THREADS)
__global__ void ghd_main(const float* __restrict__ prob_map,
                         const float* __restrict__ prob_y,
                         const float* __restrict__ gt,
                         const int*   __restrict__ osz,
                         float*       __restrict__ ws) {
    const int t    = blockIdx.x;   // tile
    const int b    = blockIdx.y;   // batch
    const int tid  = threadIdx.x;
    const int lane = tid & 63;
    const int wave = tid >> 6;

    __shared__ float4 gdat[GG];        // (ny0, ny1, py, py^2)
    __shared__ float4 sdat[TILE];      // (nx0, nx1, p, base) per pixel
    __shared__ float  wmin[4][GG];
    __shared__ float  s_t1[4], s_ne[4];

    const float nf0 = (float)osz[2 * b]     * (1.0f / HH);
    const float nf1 = (float)osz[2 * b + 1] * (1.0f / WW);

    if (tid < GG) {
        float py = prob_y[b * GG + tid];
        gdat[tid] = make_float4(nf0 * gt[(b * GG + tid) * 2],
                                nf1 * gt[(b * GG + tid) * 2 + 1],
                                py, py * py);
    }

    // ---- stage this block's tile; keep own 4 pixels in registers ----
    const int   pid0 = t * TILE + tid * 4;
    const float4 p4  = ((const float4*)(prob_map + (size_t)b * PP))[pid0 >> 2];
    const float nx0  = nf0 * (float)(pid0 >> 9);
    const float j0   = (float)(pid0 & (WW - 1));
    const float nx1a = nf1 * j0;
    const float nx1b = nf1 * (j0 + 1.0f);
    const float nx1c = nf1 * (j0 + 2.0f);
    const float nx1d = nf1 * (j0 + 3.0f);
    const float bsa = fmaf(-p4.x, MAX_DIST, MAX_DIST);
    const float bsb = fmaf(-p4.y, MAX_DIST, MAX_DIST);
    const float bsc = fmaf(-p4.z, MAX_DIST, MAX_DIST);
    const float bsd = fmaf(-p4.w, MAX_DIST, MAX_DIST);
    sdat[tid * 4 + 0] = make_float4(nx0, nx1a, p4.x, bsa);
    sdat[tid * 4 + 1] = make_float4(nx0, nx1b, p4.y, bsb);
    sdat[tid * 4 + 2] = make_float4(nx0, nx1c, p4.z, bsc);
    sdat[tid * 4 + 3] = make_float4(nx0, nx1d, p4.w, bsd);
    __syncthreads();

    // ================= A: term-1 on own 4 pixels (registers + gdat) ==========
    float ma = 3.4e38f, mb = 3.4e38f, mc = 3.4e38f, md = 3.4e38f;
#pragma unroll 16
    for (int g = 0; g < GG; ++g) {
        float4 gd  = gdat[g];
        float  dx  = nx0 - gd.x;
        float  dx2 = dx * dx;
        float  da = nx1a - gd.y, db = nx1b - gd.y;
        float  dc = nx1c - gd.y, dd = nx1d - gd.y;
        ma = fminf(ma, gd.w * fmaf(da, da, dx2));   // min_g (py^2 * d^2)
        mb = fminf(mb, gd.w * fmaf(db, db, dx2));
        mc = fminf(mc, gd.w * fmaf(dc, dc, dx2));
        md = fminf(md, gd.w * fmaf(dd, dd, dx2));
    }
    float t1 = p4.x * __builtin_amdgcn_sqrtf(ma) + p4.y * __builtin_amdgcn_sqrtf(mb)
             + p4.z * __builtin_amdgcn_sqrtf(mc) + p4.w * __builtin_amdgcn_sqrtf(md);
    float ne = p4.x + p4.y + p4.z + p4.w;

    // ================= B: term-2, lane owns g, wave scans tile quarter =======
    const float4 gme = gdat[lane];      // gx, gy, py
    float gmin = 3.4e38f;
    const float4* __restrict__ tp = &sdat[wave * (TILE / 4)];
#pragma unroll 4
    for (int k = 0; k < TILE / 4; k += 4) {
        float4 x0 = tp[k], x1 = tp[k + 1], x2 = tp[k + 2], x3 = tp[k + 3];
        float mbse = fminf(fminf(x0.w, x1.w), fminf(x2.w, x3.w));
        if (!__all(mbse >= gmin)) {
            float d0x = x0.x - gme.x, d0y = x0.y - gme.y;
            float d1x = x1.x - gme.x, d1y = x1.y - gme.y;
            float d2x = x2.x - gme.x, d2y = x2.y - gme.y;
            float d3x = x3.x - gme.x, d3y = x3.y - gme.y;
            float e0 = __builtin_amdgcn_sqrtf(fmaf(d0x, d0x, d0y * d0y));
            float e1 = __builtin_amdgcn_sqrtf(fmaf(d1x, d1x, d1y * d1y));
            float e2 = __builtin_amdgcn_sqrtf(fmaf(d2x, d2x, d2y * d2y));
            float e3 = __builtin_amdgcn_sqrtf(fmaf(d3x, d3x, d3y * d3y));
            gmin = fminf(gmin, fmaf(x0.z * gme.z, e0, x0.w));
            gmin = fminf(gmin, fmaf(x1.z * gme.z, e1, x1.w));
            gmin = fminf(gmin, fmaf(x2.z * gme.z, e2, x2.w));
            gmin = fminf(gmin, fmaf(x3.z * gme.z, e3, x3.w));
        }
    }
    wmin[wave][lane] = gmin;

    // ================= block reductions =====================================
#pragma unroll
    for (int off = 1; off < 64; off <<= 1) {
        t1 += __shfl_xor(t1, off);
        ne += __shfl_xor(ne, off);
    }
    if (lane == 0) { s_t1[wave] = t1; s_ne[wave] = ne; }
    __syncthreads();

    if (tid == 0) {
        ws[256  + b * NT + t] = s_t1[0] + s_t1[1] + s_t1[2] + s_t1[3];
        ws[1280 + b * NT + t] = s_ne[0] + s_ne[1] + s_ne[2] + s_ne[3];
    }
    if (tid < GG) {
        float v = fminf(fminf(wmin[0][tid], wmin[1][tid]),
                        fminf(wmin[2][tid], wmin[3][tid]));
        // device-scope atomicMin on uint bits: order-preserving for floats >= 0
        atomicMin(reinterpret_cast<unsigned*>(ws) + b * GG + tid, __float_as_uint(v));
    }
}

__global__ void ghd_final(const float* __restrict__ prob_y,
                          const float* __restrict__ ws,
                          float*       __restrict__ out) {
    // 256 threads: wave b handles batch b, lane = g
    const int tid = threadIdx.x;
    const int b = tid >> 6;
    const int g = tid & 63;

    float mv  = __uint_as_float(reinterpret_cast<const unsigned*>(ws)[b * GG + g]);
    float py  = prob_y[b * GG + g];
    float pyf = (py > 0.2f) ? py : 0.0f;

    // t1 / ne partial sums: lane loads float4 (64 lanes x 4 = 256 tiles)
    float4 tv = ((const float4*)(ws + 256))[b * (NT / 4) + g];
    float4 nv = ((const float4*)(ws + 1280))[b * (NT / 4) + g];
    float t1s = tv.x + tv.y + tv.z + tv.w;
    float nes = nv.x + nv.y + nv.z + nv.w;

#pragma unroll
    for (int off = 1; off < 64; off <<= 1) {
        mv  += __shfl_xor(mv, off);
        pyf += __shfl_xor(pyf, off);
        t1s += __shfl_xor(t1s, off);
        nes += __shfl_xor(nes, off);
    }
    __shared__ float res[4];
    if (g == 0) res[b] = t1s / (nes + EPSV) + mv / (pyf + EPSV);
    __syncthreads();
    if (tid == 0) out[0] = 0.25f * (res[0] + res[1] + res[2] + res[3]);
}

extern "C" void kernel_launch(void* const* d_in, const int* in_sizes, int n_in,
                              void* d_out, int out_size, void* d_ws, size_t ws_size,
                              hipStream_t stream) {
    const float* prob_map = (const float*)d_in[0];
    const float* prob_y   = (const float*)d_in[1];
    const float* gt       = (const float*)d_in[2];
    const int*   osz      = (const int*)d_in[3];
    float* out = (float*)d_out;
    float* ws  = (float*)d_ws;

    // init gmin bits to 0x7f7f7f7f (3.39e38) — larger than any dense value (<= ~1448)
    hipMemsetAsync(ws, 0x7f, BB * GG * sizeof(unsigned), stream);

    dim3 grid(NT, BB);
    ghd_main<<<grid, THREADS, 0, stream>>>(prob_map, prob_y, gt, osz, ws);
    ghd_final<<<1, 256, 0, stream>>>(prob_y, ws, out);
}

// Round 11
// 86.444 us; speedup vs baseline: 1.4491x; 1.0803x over previous
//
#include <hip/hip_runtime.h>
#include <math.h>

#define HH 512
#define WW 512
#define PP (HH * WW)          // 262144 pixels
#define GG 64                 // gt points per batch
#define BB 4                  // batches
#define THREADS 512
#define TILE 1024             // pixels per block
#define NT (PP / TILE)        // 256 tiles per batch
#define MAX_DIST 724.0773439350246f   // sqrt(512^2 + 512^2)
#define EPSV 1e-6f
#define BIGF 3.4e38f

// ws layout:
//   gm  uint bits [BB][GG] : ws[0    .. 255]    (init 0x7f7f7f7f via memset — > any dense value)
//   t1p [BB][NT]           : ws[256  .. 1279]   (write-only partials, no init)
//   nep [BB][NT]           : ws[1280 .. 2303]

__launch_bounds__(THREADS, 8)
__global__ void ghd_main(const float* __restrict__ prob_map,
                         const float* __restrict__ prob_y,
                         const float* __restrict__ gt,
                         const int*   __restrict__ osz,
                         float*       __restrict__ ws) {
    const int t    = blockIdx.x;   // tile
    const int b    = blockIdx.y;   // batch
    const int tid  = threadIdx.x;
    const int lane = tid & 63;
    const int wave = tid >> 6;     // 8 waves

    __shared__ float4 gdat[GG];                 // (ny0, ny1, py, py^2)
    __shared__ __align__(16) float sp[TILE];    // p only — coords derived from index
    __shared__ float  wmin[8][GG];
    __shared__ float  s_t1[8], s_ne[8];

    const float nf0 = (float)osz[2 * b]     * (1.0f / HH);
    const float nf1 = (float)osz[2 * b + 1] * (1.0f / WW);

    if (tid < GG) {
        float py = prob_y[b * GG + tid];
        gdat[tid] = make_float4(nf0 * gt[(b * GG + tid) * 2],
                                nf1 * gt[(b * GG + tid) * 2 + 1],
                                py, py * py);
    }
    // stage p: 512 threads x float2 = 1024 floats, coalesced
    ((float2*)sp)[tid] = ((const float2*)(prob_map + (size_t)b * PP + t * TILE))[tid];
    __syncthreads();

    // ================= A: term-1, 2 own pixels (same row, adjacent cols) =====
    const int   pid0 = t * TILE + tid * 2;
    const float p0 = sp[tid * 2], p1 = sp[tid * 2 + 1];
    const float nx0  = nf0 * (float)(pid0 >> 9);
    const float nx1a = nf1 * (float)(pid0 & (WW - 1));
    float ma = BIGF, mb = BIGF;
#pragma unroll 16
    for (int g = 0; g < GG; ++g) {
        float4 gd  = gdat[g];
        float  dx  = nx0 - gd.x;
        float  dx2 = dx * dx;
        float  da  = nx1a - gd.y;
        float  db  = da + nf1;
        ma = fminf(ma, gd.w * fmaf(da, da, dx2));   // min_g (py^2 * d^2)
        mb = fminf(mb, gd.w * fmaf(db, db, dx2));
    }
    float t1 = p0 * __builtin_amdgcn_sqrtf(ma) + p1 * __builtin_amdgcn_sqrtf(mb);
    float ne = p0 + p1;

    // ================= B: term-2, lane owns g, wave scans its 128-px eighth ==
    // 128-px segment lies in ONE image row -> dx^2 is loop-invariant per lane.
    const float4 gme  = gdat[lane];
    const int    s0   = wave * (TILE / 8);
    const int    pidw = t * TILE + s0;
    const float  dxw  = nf0 * (float)(pidw >> 9) - gme.x;
    const float  dx2w = dxw * dxw;
    const float  mgy  = -gme.y;
    float jf  = (float)(pidw & (WW - 1));
    float gm0 = BIGF, gm1 = BIGF;
    const float4* __restrict__ sp4 = (const float4*)(sp + s0);
#pragma unroll 8
    for (int k = 0; k < TILE / 8 / 4; ++k) {    // 32 chunks of 4 px
        float4 q = sp4[k];                       // broadcast read (p only)
        float dy0 = fmaf(nf1, jf,        mgy);
        float dy1 = fmaf(nf1, jf + 1.0f, mgy);
        float dy2 = fmaf(nf1, jf + 2.0f, mgy);
        float dy3 = fmaf(nf1, jf + 3.0f, mgy);
        float e0 = __builtin_amdgcn_sqrtf(fmaf(dy0, dy0, dx2w));
        float e1 = __builtin_amdgcn_sqrtf(fmaf(dy1, dy1, dx2w));
        float e2 = __builtin_amdgcn_sqrtf(fmaf(dy2, dy2, dx2w));
        float e3 = __builtin_amdgcn_sqrtf(fmaf(dy3, dy3, dx2w));
        gm0 = fminf(gm0, fmaf(q.x * gme.z, e0, fmaf(-q.x, MAX_DIST, MAX_DIST)));
        gm1 = fminf(gm1, fmaf(q.y * gme.z, e1, fmaf(-q.y, MAX_DIST, MAX_DIST)));
        gm0 = fminf(gm0, fmaf(q.z * gme.z, e2, fmaf(-q.z, MAX_DIST, MAX_DIST)));
        gm1 = fminf(gm1, fmaf(q.w * gme.z, e3, fmaf(-q.w, MAX_DIST, MAX_DIST)));
        jf += 4.0f;
    }
    wmin[wave][lane] = fminf(gm0, gm1);

    // ================= block reductions =====================================
#pragma unroll
    for (int off = 1; off < 64; off <<= 1) {
        t1 += __shfl_xor(t1, off);
        ne += __shfl_xor(ne, off);
    }
    if (lane == 0) { s_t1[wave] = t1; s_ne[wave] = ne; }
    __syncthreads();

    if (tid == 0) {
        float st = 0.0f, sn = 0.0f;
#pragma unroll
        for (int w = 0; w < 8; ++w) { st += s_t1[w]; sn += s_ne[w]; }
        ws[256  + b * NT + t] = st;
        ws[1280 + b * NT + t] = sn;
    }
    if (tid < GG) {
        float v = wmin[0][tid];
#pragma unroll
        for (int w = 1; w < 8; ++w) v = fminf(v, wmin[w][tid]);
        // device-scope atomicMin on uint bits: order-preserving for floats >= 0
        atomicMin(reinterpret_cast<unsigned*>(ws) + b * GG + tid, __float_as_uint(v));
    }
}

__global__ void ghd_final(const float* __restrict__ prob_y,
                          const float* __restrict__ ws,
                          float*       __restrict__ out) {
    // 256 threads: wave b handles batch b, lane = g
    const int tid = threadIdx.x;
    const int b = tid >> 6;
    const int g = tid & 63;

    float mv  = __uint_as_float(reinterpret_cast<const unsigned*>(ws)[b * GG + g]);
    float py  = prob_y[b * GG + g];
    float pyf = (py > 0.2f) ? py : 0.0f;

    // t1 / ne partial sums: lane loads float4 (64 lanes x 4 = 256 tiles)
    float4 tv = ((const float4*)(ws + 256))[b * (NT / 4) + g];
    float4 nv = ((const float4*)(ws + 1280))[b * (NT / 4) + g];
    float t1s = tv.x + tv.y + tv.z + tv.w;
    float nes = nv.x + nv.y + nv.z + nv.w;

#pragma unroll
    for (int off = 1; off < 64; off <<= 1) {
        mv  += __shfl_xor(mv, off);
        pyf += __shfl_xor(pyf, off);
        t1s += __shfl_xor(t1s, off);
        nes += __shfl_xor(nes, off);
    }
    __shared__ float res[4];
    if (g == 0) res[b] = t1s / (nes + EPSV) + mv / (pyf + EPSV);
    __syncthreads();
    if (tid == 0) out[0] = 0.25f * (res[0] + res[1] + res[2] + res[3]);
}

extern "C" void kernel_launch(void* const* d_in, const int* in_sizes, int n_in,
                              void* d_out, int out_size, void* d_ws, size_t ws_size,
                              hipStream_t stream) {
    const float* prob_map = (const float*)d_in[0];
    const float* prob_y   = (const float*)d_in[1];
    const float* gt       = (const float*)d_in[2];
    const int*   osz      = (const int*)d_in[3];
    float* out = (float*)d_out;
    float* ws  = (float*)d_ws;

    // init gmin bits to 0x7f7f7f7f (3.39e38) — larger than any dense value (<= ~1448)
    hipMemsetAsync(ws, 0x7f, BB * GG * sizeof(unsigned), stream);

    dim3 grid(NT, BB);
    ghd_main<<<grid, THREADS, 0, stream>>>(prob_map, prob_y, gt, osz, ws);
    ghd_final<<<1, 256, 0, stream>>>(prob_y, ws, out);
}